// Round 4
// baseline (443.586 us; speedup 1.0000x reference)
//
#include <hip/hip_runtime.h>
#include <hip/hip_bf16.h>

// Pipeline (all fp32). Never materializes agg[N,128] nor out[N,256]:
//   G = agg^T agg (128x128 Gram), s = colsum(agg), a0 = agg row0   -- one fused kernel
//   colsum_j   = s.w_j + N b_j
//   colsumsq_j = w_j^T G w_j + 2 b_j (s.w_j) + N b_j^2              -- exact algebra
//   row0_j     = a0.w_j + b_j
//   finalize: BN(row0) -> relu -> proj -> scores
// CSR build: deg+rank pass (atomics once, int4-vectorized) -> scan -> atomic-free scatter.

#define THREADS 256
#define CHUNK 32              // rows per work-steal unit (was 64: tail imbalance)

// ---------------- degree histogram + per-edge rank (4 edges/thread) ----------------
__global__ __launch_bounds__(THREADS) void deg_rank_kernel(const int* __restrict__ ei,
                                                           int* __restrict__ deg,
                                                           int* __restrict__ rank,
                                                           int E, int N) {
    int e4 = (blockIdx.x * THREADS + threadIdx.x) * 4;
    if (e4 + 3 < E) {
        int4 d = *(const int4*)(ei + E + e4);
        int4 r;
        r.x = ((unsigned)d.x < (unsigned)N) ? atomicAdd(&deg[d.x], 1) : 0;
        r.y = ((unsigned)d.y < (unsigned)N) ? atomicAdd(&deg[d.y], 1) : 0;
        r.z = ((unsigned)d.z < (unsigned)N) ? atomicAdd(&deg[d.z], 1) : 0;
        r.w = ((unsigned)d.w < (unsigned)N) ? atomicAdd(&deg[d.w], 1) : 0;
        *(int4*)(rank + e4) = r;
    } else if (e4 < E) {
        for (int u = e4; u < E; ++u) {
            unsigned d = (unsigned)ei[E + u];
            rank[u] = (d < (unsigned)N) ? atomicAdd(&deg[d], 1) : 0;
        }
    }
}

// ---------------- scan phase 1 (per-1024 chunk) + dinv ----------------
__global__ __launch_bounds__(THREADS) void scan1_kernel(const int* __restrict__ deg,
                                                        int* __restrict__ rowptr,
                                                        int* __restrict__ bsum,
                                                        float* __restrict__ dinv, int n) {
    __shared__ int sh[THREADS];
    const int t = threadIdx.x, b = blockIdx.x;
    const int base = b * 1024 + t * 4;
    int v0 = (base + 0 < n) ? deg[base + 0] : 0;
    int v1 = (base + 1 < n) ? deg[base + 1] : 0;
    int v2 = (base + 2 < n) ? deg[base + 2] : 0;
    int v3 = (base + 3 < n) ? deg[base + 3] : 0;
    if (base + 0 < n) dinv[base + 0] = rsqrtf((float)(v0 + 1));
    if (base + 1 < n) dinv[base + 1] = rsqrtf((float)(v1 + 1));
    if (base + 2 < n) dinv[base + 2] = rsqrtf((float)(v2 + 1));
    if (base + 3 < n) dinv[base + 3] = rsqrtf((float)(v3 + 1));
    const int local = v0 + v1 + v2 + v3;
    sh[t] = local;
    __syncthreads();
    int run = local;
    for (int off = 1; off < THREADS; off <<= 1) {
        int add = (t >= off) ? sh[t - off] : 0;
        __syncthreads();
        run += add;
        sh[t] = run;
        __syncthreads();
    }
    const int excl = run - local;
    if (base + 0 < n) rowptr[base + 0] = excl;
    if (base + 1 < n) rowptr[base + 1] = excl + v0;
    if (base + 2 < n) rowptr[base + 2] = excl + v0 + v1;
    if (base + 3 < n) rowptr[base + 3] = excl + v0 + v1 + v2;
    if (t == 0) bsum[b] = sh[THREADS - 1];
}

// ---------------- scan phase 2 (chunk offsets) + zero small buffers ----------------
__global__ __launch_bounds__(THREADS) void scan2_kernel(const int* __restrict__ bsum,
                                                        int* __restrict__ boff, int nb,
                                                        float* __restrict__ colsumS,
                                                        float* __restrict__ G,
                                                        int* __restrict__ workctr) {
    __shared__ int sh[THREADS];
    const int t = threadIdx.x;
    const int local = (t < nb) ? bsum[t] : 0;
    sh[t] = local;
    __syncthreads();
    int run = local;
    for (int off = 1; off < THREADS; off <<= 1) {
        int add = (t >= off) ? sh[t - off] : 0;
        __syncthreads();
        run += add;
        sh[t] = run;
        __syncthreads();
    }
    boff[t] = run - local;
    if (t < 128) colsumS[t] = 0.f;
    if (t == 0) *workctr = 0;
    for (int u = t; u < 16384; u += THREADS) G[u] = 0.f;
}

// ---------------- atomic-free counting-sort scatter (4 edges/thread) ----------------
__global__ __launch_bounds__(THREADS) void scatter_kernel(const int* __restrict__ ei,
                                                          const int* __restrict__ rowptr,
                                                          const int* __restrict__ boff,
                                                          const int* __restrict__ rank,
                                                          int* __restrict__ csr,
                                                          int E, int N) {
    int e4 = (blockIdx.x * THREADS + threadIdx.x) * 4;
    if (e4 + 3 < E) {
        int4 d = *(const int4*)(ei + E + e4);
        int4 s = *(const int4*)(ei + e4);
        int4 r = *(const int4*)(rank + e4);
        if ((unsigned)d.x < (unsigned)N) {
            int p = rowptr[d.x] + boff[d.x >> 10] + r.x;
            if ((unsigned)p < (unsigned)E) csr[p] = s.x;
        }
        if ((unsigned)d.y < (unsigned)N) {
            int p = rowptr[d.y] + boff[d.y >> 10] + r.y;
            if ((unsigned)p < (unsigned)E) csr[p] = s.y;
        }
        if ((unsigned)d.z < (unsigned)N) {
            int p = rowptr[d.z] + boff[d.z >> 10] + r.z;
            if ((unsigned)p < (unsigned)E) csr[p] = s.z;
        }
        if ((unsigned)d.w < (unsigned)N) {
            int p = rowptr[d.w] + boff[d.w >> 10] + r.w;
            if ((unsigned)p < (unsigned)E) csr[p] = s.w;
        }
    } else if (e4 < E) {
        for (int u = e4; u < E; ++u) {
            unsigned d = (unsigned)ei[E + u];
            if (d < (unsigned)N) {
                int p = rowptr[d] + boff[d >> 10] + rank[u];
                if ((unsigned)p < (unsigned)E) csr[p] = ei[u];
            }
        }
    }
}

// ---------------- fused aggregate + Gram (syrk) + colsum + row0 ----------------
// 512 threads, CHUNK=32-row work-steal units. Gather rows into LDS (17 KB);
// register-resident 8x4 G partial per thread (16x32 grid); per-block Gpart
// write at end; s via t<128 column sums.
__global__ __launch_bounds__(512) void agg_syrk_kernel(
        const float* __restrict__ x, const int* __restrict__ rowptr,
        const int* __restrict__ boff, const int* __restrict__ csr,
        const float* __restrict__ dinv, int* __restrict__ workctr,
        float* __restrict__ Gpart, float* __restrict__ colsumS,
        float* __restrict__ agg0, int n, int E, int NC) {
    __shared__ float Asm[CHUNK * 132];   // 32 rows x 128 cols, stride 132
    __shared__ int sh_c;
    const int t = threadIdx.x;
    const int lane = t & 63, wv = t >> 6;
    const int p0 = (t >> 5) * 8;      // 16 p-groups x 8
    const int q0 = (t & 31) * 4;      // 32 q-groups x 4
    const float* xl = x + lane * 2;

    float acc[8][4];
#pragma unroll
    for (int i = 0; i < 8; ++i)
#pragma unroll
        for (int j = 0; j < 4; ++j) acc[i][j] = 0.f;
    float s_acc = 0.f;

    for (;;) {
        if (t == 0) sh_c = atomicAdd(workctr, 1);
        __syncthreads();
        const int c = sh_c;
        if (c >= NC) break;

        // gather: wave wv aggregates rows wv*4 .. wv*4+3 of this chunk
        for (int rr = 0; rr < CHUNK / 8; ++rr) {
            const int r = wv * (CHUNK / 8) + rr;
            const int i = c * CHUNK + r;
            float ax = 0.f, ay = 0.f;
            if (i < n) {
                const int e0 = rowptr[i] + boff[i >> 10];
                const int e1 = (i + 1 < n) ? rowptr[i + 1] + boff[(i + 1) >> 10] : E;
                const float di = dinv[i];
                const float2 xs = *(const float2*)(xl + (size_t)i * 128);
                ax = di * xs.x; ay = di * xs.y;           // self-loop (inner)
                int e = e0;
                for (; e + 8 <= e1; e += 8) {             // 8-deep MLP
                    int ss[8]; float ww[8]; float2 pv[8];
#pragma unroll
                    for (int u = 0; u < 8; ++u) {
                        int s = csr[e + u];
                        ss[u] = ((unsigned)s < (unsigned)n) ? s : 0;
                    }
#pragma unroll
                    for (int u = 0; u < 8; ++u) ww[u] = dinv[ss[u]];
#pragma unroll
                    for (int u = 0; u < 8; ++u)
                        pv[u] = *(const float2*)(xl + (size_t)ss[u] * 128);
#pragma unroll
                    for (int u = 0; u < 8; ++u) {
                        ax = fmaf(ww[u], pv[u].x, ax);
                        ay = fmaf(ww[u], pv[u].y, ay);
                    }
                }
                for (; e < e1; ++e) {
                    int s = csr[e];
                    s = ((unsigned)s < (unsigned)n) ? s : 0;
                    float w = dinv[s];
                    float2 p = *(const float2*)(xl + (size_t)s * 128);
                    ax = fmaf(w, p.x, ax);
                    ay = fmaf(w, p.y, ay);
                }
                ax *= di; ay *= di;
            }
            *(float2*)(Asm + r * 132 + lane * 2) = make_float2(ax, ay);
        }
        __syncthreads();

        if (c == 0 && t < 32)
            *(float4*)(agg0 + t * 4) = *(const float4*)(Asm + t * 4);

        // syrk: G += Asm^T Asm  (inner dim = CHUNK rows)
#pragma unroll 4
        for (int r = 0; r < CHUNK; ++r) {
            const float* row = Asm + r * 132;
            float4 a0 = *(const float4*)(row + p0);
            float4 a1 = *(const float4*)(row + p0 + 4);
            float4 bq = *(const float4*)(row + q0);
            float ap[8] = {a0.x, a0.y, a0.z, a0.w, a1.x, a1.y, a1.z, a1.w};
            float aq[4] = {bq.x, bq.y, bq.z, bq.w};
#pragma unroll
            for (int pp = 0; pp < 8; ++pp)
#pragma unroll
                for (int qq = 0; qq < 4; ++qq)
                    acc[pp][qq] = fmaf(ap[pp], aq[qq], acc[pp][qq]);
        }
        if (t < 128) {   // column sums for s
            float sa = 0.f;
#pragma unroll 4
            for (int r = 0; r < CHUNK; ++r) sa += Asm[r * 132 + t];
            s_acc += sa;
        }
        __syncthreads();
    }

    float* gp = Gpart + (size_t)blockIdx.x * 16384;
#pragma unroll
    for (int pp = 0; pp < 8; ++pp)
        *(float4*)(gp + (p0 + pp) * 128 + q0) =
            make_float4(acc[pp][0], acc[pp][1], acc[pp][2], acc[pp][3]);
    if (t < 128) atomicAdd(&colsumS[t], s_acc);
}

// ---------------- reduce Gpart -> G (8 segments, atomic combine) ----------------
__global__ __launch_bounds__(THREADS) void greduce_kernel(const float* __restrict__ Gpart,
                                                          float* __restrict__ G, int NB) {
    const int seg = blockIdx.x >> 4;                       // 8 segments
    const int i4 = (blockIdx.x & 15) * THREADS + threadIdx.x;   // 0..4095
    const int b0 = (seg * NB) / 8, b1 = ((seg + 1) * NB) / 8;
    float4 a = make_float4(0.f, 0.f, 0.f, 0.f);
    for (int b = b0; b < b1; ++b) {
        float4 v = *(const float4*)(Gpart + (size_t)b * 16384 + i4 * 4);
        a.x += v.x; a.y += v.y; a.z += v.z; a.w += v.w;
    }
    atomicAdd(&G[i4 * 4 + 0], a.x);
    atomicAdd(&G[i4 * 4 + 1], a.y);
    atomicAdd(&G[i4 * 4 + 2], a.z);
    atomicAdd(&G[i4 * 4 + 3], a.w);
}

// ---------------- per-column stats from G, s, agg0 (one block per j) ----------------
__global__ __launch_bounds__(THREADS) void stats_kernel(
        const float* __restrict__ G, const float* __restrict__ W,
        const float* __restrict__ bias, const float* __restrict__ colsumS,
        const float* __restrict__ agg0, float* __restrict__ colsum,
        float* __restrict__ colsumsq, float* __restrict__ row0, int n) {
    __shared__ float wsm[128];
    __shared__ float red[THREADS], red2[THREADS], red3[THREADS];
    const int t = threadIdx.x, j = blockIdx.x;
    if (t < 128) wsm[t] = W[t * 256 + j];
    __syncthreads();
    float part = 0.f;
    const float wq = wsm[t & 127];
    const int pbase = t >> 7;          // 0 or 1
#pragma unroll 8
    for (int u = 0; u < 64; ++u)       // f = u*256 + t, coalesced
        part = fmaf(G[u * 256 + t], wsm[pbase + u * 2], part);
    red[t] = part * wq;
    red2[t] = (t < 128) ? colsumS[t] * wsm[t] : 0.f;
    red3[t] = (t < 128) ? agg0[t] * wsm[t] : 0.f;
    __syncthreads();
    for (int s = 128; s > 0; s >>= 1) {
        if (t < s) { red[t] += red[t + s]; red2[t] += red2[t + s]; red3[t] += red3[t + s]; }
        __syncthreads();
    }
    if (t == 0) {
        const float b = bias[j];
        const float sw = red2[0];
        colsum[j]   = sw + (float)n * b;
        colsumsq[j] = red[0] + 2.f * b * sw + (float)n * b * b;
        row0[j]     = red3[0] + b;
    }
}

// ---------------- finalize: BN(row0)+relu -> proj -> scores ----------------
__global__ __launch_bounds__(THREADS) void finalize_kernel(
        const float* __restrict__ colsum, const float* __restrict__ colsumsq,
        const float* __restrict__ row0, const float* __restrict__ gamma,
        const float* __restrict__ beta, const float* __restrict__ proj_w,
        const float* __restrict__ proj_b, const float* __restrict__ emb,
        float* __restrict__ out, int n_nodes, int n_items) {
    __shared__ float x0[256];
    __shared__ float rsu[128];
    const int t = threadIdx.x;
    const float invn = 1.0f / (float)n_nodes;
    {
        float mean = colsum[t] * invn;
        float var = colsumsq[t] * invn - mean * mean;
        float r = rsqrtf(var + 1e-5f);
        float v = gamma[t] * (row0[t] - mean) * r + beta[t];
        x0[t] = v > 0.f ? v : 0.f;
    }
    __syncthreads();
    if (t < 128) {
        float sacc = proj_b[t];
        for (int c = 0; c < 256; ++c) sacc = fmaf(x0[c], proj_w[c * 128 + t], sacc);
        rsu[t] = sacc;
        out[128 + t] = sacc;      // rsu_embedding
    }
    __syncthreads();
    if (t < n_items) {
        float sacc = 0.f;
        for (int j = 0; j < 128; ++j) sacc = fmaf(emb[t * 128 + j], rsu[j], sacc);
        out[t] = sacc;            // scores
    }
}

extern "C" void kernel_launch(void* const* d_in, const int* in_sizes, int n_in,
                              void* d_out, int out_size, void* d_ws, size_t ws_size,
                              hipStream_t stream) {
    const float* node_feature = (const float*)d_in[0];
    const int*   edge_index   = (const int*)d_in[1];
    // d_in[2] items_ready_to_cache: unused (reference uses arange(n_items))
    const float* gcn_w  = (const float*)d_in[3];
    const float* gcn_b  = (const float*)d_in[4];
    const float* bn_g   = (const float*)d_in[5];
    const float* bn_b   = (const float*)d_in[6];
    const float* emb    = (const float*)d_in[7];
    const float* proj_w = (const float*)d_in[8];
    const float* proj_b = (const float*)d_in[9];
    float* out = (float*)d_out;

    const int N = in_sizes[0] / 128;
    const int E = in_sizes[1] / 2;
    const int n_items = in_sizes[2];

    // workspace carve (256B aligned); Gpart last, NB sized to what fits
    char* base = (char*)d_ws;
    size_t off = 0;
    auto alloc = [&](size_t bytes) -> void* {
        void* p = (void*)(base + off);
        off += (bytes + 255) & ~(size_t)255;
        return p;
    };
    int*   deg      = (int*)alloc((size_t)N * 4);
    int*   rank     = (int*)alloc((size_t)E * 4);
    int*   rowptr   = (int*)alloc((size_t)N * 4);
    int*   bsum     = (int*)alloc(256 * 4);
    int*   boff     = (int*)alloc(256 * 4);
    float* dinv     = (float*)alloc((size_t)N * 4);
    int*   csr      = (int*)alloc((size_t)E * 4);
    float* colsumS  = (float*)alloc(128 * 4);
    float* agg0     = (float*)alloc(128 * 4);
    float* G        = (float*)alloc(16384 * 4);
    float* colsum   = (float*)alloc(256 * 4);
    float* colsumsq = (float*)alloc(256 * 4);
    float* row0     = (float*)alloc(256 * 4);
    int*   workctr  = (int*)alloc(256);
    int NB = (int)((ws_size > off) ? ((ws_size - off) / (16384 * 4)) : 0);
    if (NB > 1024) NB = 1024;          // 4 blocks/CU resident cap
    if (NB < 8) NB = 8;                // ws known >= ~60 MB; 8 always fits
    float* Gpart    = (float*)alloc((size_t)NB * 16384 * 4);

    const int nbE4 = (E / 4 + THREADS - 1) / THREADS;
    const int nchunks = (N + 1023) >> 10;     // <= 256 for N <= 262144
    const int NC = (N + CHUNK - 1) / CHUNK;

    hipMemsetAsync(deg, 0, (size_t)N * 4, stream);

    deg_rank_kernel<<<nbE4, THREADS, 0, stream>>>(edge_index, deg, rank, E, N);
    scan1_kernel<<<nchunks, THREADS, 0, stream>>>(deg, rowptr, bsum, dinv, N);
    scan2_kernel<<<1, THREADS, 0, stream>>>(bsum, boff, nchunks, colsumS, G, workctr);
    scatter_kernel<<<nbE4, THREADS, 0, stream>>>(edge_index, rowptr, boff, rank, csr, E, N);
    agg_syrk_kernel<<<NB, 512, 0, stream>>>(node_feature, rowptr, boff, csr, dinv,
                                            workctr, Gpart, colsumS, agg0, N, E, NC);
    greduce_kernel<<<128, THREADS, 0, stream>>>(Gpart, G, NB);
    stats_kernel<<<256, THREADS, 0, stream>>>(G, gcn_w, gcn_b, colsumS, agg0,
                                              colsum, colsumsq, row0, N);
    finalize_kernel<<<1, THREADS, 0, stream>>>(colsum, colsumsq, row0, bn_g, bn_b,
                                               proj_w, proj_b, emb, out, N, n_items);
}